// Round 1
// baseline (566.772 us; speedup 1.0000x reference)
//
#include <hip/hip_runtime.h>
#include <cmath>

using u16 = unsigned short;
using u32 = unsigned int;
using bf16x8 = __attribute__((ext_vector_type(8))) __bf16;
using f32x4  = __attribute__((ext_vector_type(4))) float;

__device__ inline u16 f2bf(float f) {
  u32 u = __float_as_uint(f);
  u32 r = (u + 0x7fffu + ((u >> 16) & 1u)) >> 16;  // RNE
  return (u16)r;
}

// ---------------- LayerNorm: x[row][1024] f32 -> xn bf16 ----------------
__global__ __launch_bounds__(256) void ln_kernel(
    const float* __restrict__ x, const float* __restrict__ w,
    const float* __restrict__ b, u16* __restrict__ xn) {
  int row = blockIdx.x;
  const float4* xr = (const float4*)(x + (size_t)row * 1024);
  float4 v = xr[threadIdx.x];
  float s  = v.x + v.y + v.z + v.w;
  float ss = v.x * v.x + v.y * v.y + v.z * v.z + v.w * v.w;
  int lane = threadIdx.x & 63, wave = threadIdx.x >> 6;
#pragma unroll
  for (int o = 32; o >= 1; o >>= 1) {
    s  += __shfl_xor(s, o, 64);
    ss += __shfl_xor(ss, o, 64);
  }
  __shared__ float rs[4], rq[4];
  if (lane == 0) { rs[wave] = s; rq[wave] = ss; }
  __syncthreads();
  s  = rs[0] + rs[1] + rs[2] + rs[3];
  ss = rq[0] + rq[1] + rq[2] + rq[3];
  float mean = s * (1.0f / 1024.0f);
  float var  = ss * (1.0f / 1024.0f) - mean * mean;
  float rstd = rsqrtf(var + 1e-5f);
  int c = threadIdx.x * 4;
  ushort4 ov;
  ov.x = f2bf((v.x - mean) * rstd * w[c + 0] + b[c + 0]);
  ov.y = f2bf((v.y - mean) * rstd * w[c + 1] + b[c + 1]);
  ov.z = f2bf((v.z - mean) * rstd * w[c + 2] + b[c + 2]);
  ov.w = f2bf((v.w - mean) * rstd * w[c + 3] + b[c + 3]);
  ((ushort4*)(xn + (size_t)row * 1024))[threadIdx.x] = ov;
}

// ---------------- weight transpose f32 [R][C] -> bf16 [C][R] ----------------
__global__ __launch_bounds__(256) void transpose_w(
    const float* __restrict__ in, u16* __restrict__ out, int R, int C) {
  __shared__ float tile[32][33];
  int c0 = blockIdx.x * 32, r0 = blockIdx.y * 32;
  int tx = threadIdx.x, ty = threadIdx.y;  // block (32,8)
#pragma unroll
  for (int i = 0; i < 32; i += 8)
    tile[ty + i][tx] = in[(size_t)(r0 + ty + i) * C + c0 + tx];
  __syncthreads();
#pragma unroll
  for (int i = 0; i < 32; i += 8)
    out[(size_t)(c0 + ty + i) * R + r0 + tx] = f2bf(tile[tx][ty + i]);
}

// ---------------- V transpose bf16: per batch [2048][1024] -> [1024][2048] ----
__global__ __launch_bounds__(256) void transpose_v(
    const u16* __restrict__ in, u16* __restrict__ out) {
  const u16* inb = in + (size_t)blockIdx.z * 2048 * 1024;
  u16* outb      = out + (size_t)blockIdx.z * 1024 * 2048;
  __shared__ u16 tile[32][33];
  int c0 = blockIdx.x * 32, r0 = blockIdx.y * 32;
  int tx = threadIdx.x, ty = threadIdx.y;
#pragma unroll
  for (int i = 0; i < 32; i += 8)
    tile[ty + i][tx] = inb[(size_t)(r0 + ty + i) * 1024 + c0 + tx];
  __syncthreads();
#pragma unroll
  for (int i = 0; i < 32; i += 8)
    outb[(size_t)(c0 + ty + i) * 2048 + r0 + tx] = tile[tx][ty + i];
}

// ---------------- masked row softmax over scores fp32, writes P bf16 in-place --
// row s attends to t in [s, 2047]; P[t<s] = 0. P stored as bf16 at row base
// (row stride stays 2048 fp32 = 4096 bf16 elements).
__global__ __launch_bounds__(256) void softmax_kernel(float* __restrict__ scores) {
  int row = blockIdx.x;
  int s = row & 2047;
  float* srow = scores + (size_t)row * 2048;
  int tid = threadIdx.x;
  int lane = tid & 63, wave = tid >> 6;
  const float FINF = __builtin_inff();
  float x[8];
  float m = -FINF;
#pragma unroll
  for (int i = 0; i < 8; i++) {
    int t = s + tid + i * 256;
    float v = -FINF;
    if (t < 2048) {
      v = srow[t];
      v = fminf(fmaxf(v, -1.0e9f), 1.0e9f);  // CLAMP
    }
    x[i] = v;
    m = fmaxf(m, v);
  }
#pragma unroll
  for (int o = 32; o >= 1; o >>= 1) m = fmaxf(m, __shfl_xor(m, o, 64));
  __shared__ float rm[4], rsum[4];
  if (lane == 0) rm[wave] = m;
  __syncthreads();
  m = fmaxf(fmaxf(rm[0], rm[1]), fmaxf(rm[2], rm[3]));
  float sum = 0.f;
#pragma unroll
  for (int i = 0; i < 8; i++) {
    x[i] = __expf(x[i] - m);  // exp(-inf - m) = 0 for padding
    sum += x[i];
  }
#pragma unroll
  for (int o = 32; o >= 1; o >>= 1) sum += __shfl_xor(sum, o, 64);
  if (lane == 0) rsum[wave] = sum;
  __syncthreads();
  sum = rsum[0] + rsum[1] + rsum[2] + rsum[3];
  float inv = 1.0f / sum;
  u16* prow = (u16*)srow;  // bf16 row overwrites first half of fp32 row (all reads done)
  for (int t = tid; t < s; t += 256) prow[t] = 0;
#pragma unroll
  for (int i = 0; i < 8; i++) {
    int t = s + tid + i * 256;
    if (t < 2048) prow[t] = f2bf(x[i] * inv);
  }
}

// ---------------- bf16 GEMM, B^T layout: C[M,N] = A[M,K] * Bt[N,K]^T ----------
// 128x128 tile, BK=64, 4 waves (2x2 of 64x64), mfma_f32_16x16x32_bf16,
// global_load_lds width 16 staging (m97 structure).
// MODE 0: plain. MODE 1: QK — skip tiles with tj<ti (fully masked).
// MODE 2: PV — k-loop starts at ti*128 (t >= s-tile start; P is 0 for t<s).
// OUTF32: 1 -> fp32 C, 0 -> bf16 C.
template <int OUTF32, int MODE>
__global__ __launch_bounds__(256, 2) void gemm_bt(
    const u16* __restrict__ A, const u16* __restrict__ B, void* __restrict__ Cv,
    const float* __restrict__ bias, int K, int lda, int ldb, int ldc,
    float scale, long long sA, long long sB, long long sC) {
  int ti = blockIdx.y, tj = blockIdx.x, bz = blockIdx.z;
  if (MODE == 1 && tj < ti) return;  // fully-masked score tile

  const u16* Ab = A + (size_t)bz * (size_t)sA;
  const u16* Bb = B + (size_t)bz * (size_t)sB;

  __shared__ u16 As[128 * 64];
  __shared__ u16 Bs[128 * 64];

  int tid = threadIdx.x;
  int wave = tid >> 6, lane = tid & 63;
  int wr = wave >> 1, wc = wave & 1;

  f32x4 acc[4][4] = {};

  int k0 = (MODE == 2) ? ti * 128 : 0;

  int lrow = lane >> 3;        // 0..7 row within 8-row segment
  int lcol = (lane & 7) * 8;   // element col within 64-wide k slice
  const int arow0 = ti * 128, brow0 = tj * 128;
  const int fr = lane & 15;          // fragment row/col index
  const int fk = (lane >> 4) * 8;    // fragment k offset

  for (int kt = k0; kt < K; kt += 64) {
#pragma unroll
    for (int i = 0; i < 4; i++) {
      int seg = wave * 4 + i;  // 0..15, wave-uniform
      int r = seg * 8 + lrow;
      const u16* ga = Ab + (size_t)(arow0 + r) * lda + kt + lcol;
      __builtin_amdgcn_global_load_lds(
          (const __attribute__((address_space(1))) void*)ga,
          (__attribute__((address_space(3))) void*)&As[seg * 512], 16, 0, 0);
      const u16* gb = Bb + (size_t)(brow0 + r) * ldb + kt + lcol;
      __builtin_amdgcn_global_load_lds(
          (const __attribute__((address_space(1))) void*)gb,
          (__attribute__((address_space(3))) void*)&Bs[seg * 512], 16, 0, 0);
    }
    __syncthreads();
#pragma unroll
    for (int kk = 0; kk < 2; kk++) {
      bf16x8 aF[4], bF[4];
      int ko = kk * 32 + fk;
#pragma unroll
      for (int m = 0; m < 4; m++)
        aF[m] = *(const bf16x8*)&As[(wr * 64 + m * 16 + fr) * 64 + ko];
#pragma unroll
      for (int n = 0; n < 4; n++)
        bF[n] = *(const bf16x8*)&Bs[(wc * 64 + n * 16 + fr) * 64 + ko];
#pragma unroll
      for (int m = 0; m < 4; m++)
#pragma unroll
        for (int n = 0; n < 4; n++)
          acc[m][n] = __builtin_amdgcn_mfma_f32_16x16x32_bf16(aF[m], bF[n], acc[m][n], 0, 0, 0);
    }
    __syncthreads();
  }

  // epilogue: C/D layout col=lane&15, row=(lane>>4)*4+j
  int orow0 = ti * 128 + wr * 64 + (lane >> 4) * 4;
  int ocol0 = tj * 128 + wc * 64 + (lane & 15);
#pragma unroll
  for (int m = 0; m < 4; m++) {
#pragma unroll
    for (int n = 0; n < 4; n++) {
      int col = ocol0 + n * 16;
      float bv = bias ? bias[col] : 0.0f;
#pragma unroll
      for (int j = 0; j < 4; j++) {
        int row = orow0 + m * 16 + j;
        float v = acc[m][n][j] * scale + bv;
        size_t idx = (size_t)bz * (size_t)sC + (size_t)row * ldc + col;
        if (OUTF32) ((float*)Cv)[idx] = v;
        else        ((u16*)Cv)[idx]   = f2bf(v);
      }
    }
  }
}

extern "C" void kernel_launch(void* const* d_in, const int* in_sizes, int n_in,
                              void* d_out, int out_size, void* d_ws, size_t ws_size,
                              hipStream_t stream) {
  (void)in_sizes; (void)n_in; (void)out_size;
  const float* x   = (const float*)d_in[0];
  const float* lnw = (const float*)d_in[1];
  const float* lnb = (const float*)d_in[2];
  const float* wq  = (const float*)d_in[3];
  const float* bq  = (const float*)d_in[4];
  const float* wk  = (const float*)d_in[5];
  const float* bk  = (const float*)d_in[6];
  const float* wv  = (const float*)d_in[7];
  const float* bv  = (const float*)d_in[8];
  const float* w0  = (const float*)d_in[9];
  const float* b0  = (const float*)d_in[10];
  float* out = (float*)d_out;

  const size_t ROWS = 16384;  // B*S
  char* ws = (char*)d_ws;
  size_t off = 0;
  auto alloc = [&](size_t bytes) -> void* {
    void* p = ws + off;
    off += (bytes + 255) & ~(size_t)255;
    return p;
  };
  u16* xn  = (u16*)alloc(ROWS * 1024 * 2);
  u16* wqt = (u16*)alloc((size_t)1024 * 1024 * 2);
  u16* wkt = (u16*)alloc((size_t)1024 * 1024 * 2);
  u16* wvt = (u16*)alloc((size_t)1024 * 1024 * 2);
  u16* w0t = (u16*)alloc((size_t)1024 * 1024 * 2);
  u16* Q   = (u16*)alloc(ROWS * 1024 * 2);
  u16* Km  = (u16*)alloc(ROWS * 1024 * 2);
  u16* V   = (u16*)alloc(ROWS * 1024 * 2);
  u16* Vt  = (u16*)alloc(ROWS * 1024 * 2);
  u16* H   = (u16*)alloc(ROWS * 1024 * 2);

  // scores scratch: NB batches of [2048 x 2048] fp32 at a time
  const size_t CHUNK = (size_t)2048 * 2048 * 4;
  float* scores;
  int NB;
  if (ws_size >= off + CHUNK) {
    size_t nb = (ws_size - off) / CHUNK;
    if (nb > 8) nb = 8;
    NB = (int)nb;
    scores = (float*)(ws + off);
  } else {
    // d_out is exactly 4 chunks (64 MB); safe scratch, fully overwritten at end
    scores = (float*)d_out;
    NB = 4;
  }

  ln_kernel<<<dim3(16384), dim3(256), 0, stream>>>(x, lnw, lnb, xn);
  dim3 tb(32, 8);
  transpose_w<<<dim3(32, 32), tb, 0, stream>>>(wq, wqt, 1024, 1024);
  transpose_w<<<dim3(32, 32), tb, 0, stream>>>(wk, wkt, 1024, 1024);
  transpose_w<<<dim3(32, 32), tb, 0, stream>>>(wv, wvt, 1024, 1024);
  transpose_w<<<dim3(32, 32), tb, 0, stream>>>(w0, w0t, 1024, 1024);

  gemm_bt<0, 0><<<dim3(8, 128, 1), dim3(256), 0, stream>>>(
      xn, wqt, Q, bq, 1024, 1024, 1024, 1024, 1.0f, 0, 0, 0);
  gemm_bt<0, 0><<<dim3(8, 128, 1), dim3(256), 0, stream>>>(
      xn, wkt, Km, bk, 1024, 1024, 1024, 1024, 1.0f, 0, 0, 0);
  gemm_bt<0, 0><<<dim3(8, 128, 1), dim3(256), 0, stream>>>(
      xn, wvt, V, bv, 1024, 1024, 1024, 1024, 1.0f, 0, 0, 0);

  transpose_v<<<dim3(32, 64, 8), tb, 0, stream>>>(V, Vt);

  float qk_scale = (float)(1.0 / (std::sqrt(1024.0) + 1e-9));
  for (int bA = 0; bA < 8; bA += NB) {
    int nb = 8 - bA;
    if (nb > NB) nb = NB;
    gemm_bt<1, 1><<<dim3(16, 16, nb), dim3(256), 0, stream>>>(
        Q + (size_t)bA * 2048 * 1024, Km + (size_t)bA * 2048 * 1024, scores, nullptr,
        1024, 1024, 1024, 2048, qk_scale,
        2048LL * 1024, 2048LL * 1024, 2048LL * 2048);
    softmax_kernel<<<dim3(nb * 2048), dim3(256), 0, stream>>>(scores);
    gemm_bt<0, 2><<<dim3(8, 16, nb), dim3(256), 0, stream>>>(
        (const u16*)scores, Vt + (size_t)bA * 1024 * 2048, H + (size_t)bA * 2048 * 1024, nullptr,
        2048, 4096, 2048, 1024, 1.0f,
        2048LL * 4096, 1024LL * 2048, 2048LL * 1024);
  }

  gemm_bt<1, 0><<<dim3(8, 128, 1), dim3(256), 0, stream>>>(
      H, w0t, (void*)out, b0, 1024, 1024, 1024, 1024, 1.0f, 0, 0, 0);
}

// Round 2
// 445.924 us; speedup vs baseline: 1.2710x; 1.2710x over previous
//
#include <hip/hip_runtime.h>
#include <cmath>

using u16 = unsigned short;
using u32 = unsigned int;
using bf16x8 = __attribute__((ext_vector_type(8))) __bf16;
using f32x4  = __attribute__((ext_vector_type(4))) float;

__device__ inline u16 f2bf(float f) {
  u32 u = __float_as_uint(f);
  u32 r = (u + 0x7fffu + ((u >> 16) & 1u)) >> 16;  // RNE
  return (u16)r;
}

// ---------------- LayerNorm: x[row][1024] f32 -> xn bf16 ----------------
__global__ __launch_bounds__(256) void ln_kernel(
    const float* __restrict__ x, const float* __restrict__ w,
    const float* __restrict__ b, u16* __restrict__ xn) {
  int row = blockIdx.x;
  const float4* xr = (const float4*)(x + (size_t)row * 1024);
  float4 v = xr[threadIdx.x];
  float s  = v.x + v.y + v.z + v.w;
  float ss = v.x * v.x + v.y * v.y + v.z * v.z + v.w * v.w;
  int lane = threadIdx.x & 63, wave = threadIdx.x >> 6;
#pragma unroll
  for (int o = 32; o >= 1; o >>= 1) {
    s  += __shfl_xor(s, o, 64);
    ss += __shfl_xor(ss, o, 64);
  }
  __shared__ float rs[4], rq[4];
  if (lane == 0) { rs[wave] = s; rq[wave] = ss; }
  __syncthreads();
  s  = rs[0] + rs[1] + rs[2] + rs[3];
  ss = rq[0] + rq[1] + rq[2] + rq[3];
  float mean = s * (1.0f / 1024.0f);
  float var  = ss * (1.0f / 1024.0f) - mean * mean;
  float rstd = rsqrtf(var + 1e-5f);
  int c = threadIdx.x * 4;
  ushort4 ov;
  ov.x = f2bf((v.x - mean) * rstd * w[c + 0] + b[c + 0]);
  ov.y = f2bf((v.y - mean) * rstd * w[c + 1] + b[c + 1]);
  ov.z = f2bf((v.z - mean) * rstd * w[c + 2] + b[c + 2]);
  ov.w = f2bf((v.w - mean) * rstd * w[c + 3] + b[c + 3]);
  ((ushort4*)(xn + (size_t)row * 1024))[threadIdx.x] = ov;
}

// ---------------- weight transpose f32 [R][C] -> bf16 [C][R] ----------------
__global__ __launch_bounds__(256) void transpose_w(
    const float* __restrict__ in, u16* __restrict__ out, int R, int C) {
  __shared__ float tile[32][33];
  int c0 = blockIdx.x * 32, r0 = blockIdx.y * 32;
  int tx = threadIdx.x, ty = threadIdx.y;  // block (32,8)
#pragma unroll
  for (int i = 0; i < 32; i += 8)
    tile[ty + i][tx] = in[(size_t)(r0 + ty + i) * C + c0 + tx];
  __syncthreads();
#pragma unroll
  for (int i = 0; i < 32; i += 8)
    out[(size_t)(c0 + ty + i) * R + r0 + tx] = f2bf(tile[tx][ty + i]);
}

// ---------------- V transpose bf16: per batch [2048][1024] -> [1024][2048] ----
__global__ __launch_bounds__(256) void transpose_v(
    const u16* __restrict__ in, u16* __restrict__ out) {
  const u16* inb = in + (size_t)blockIdx.z * 2048 * 1024;
  u16* outb      = out + (size_t)blockIdx.z * 1024 * 2048;
  __shared__ u16 tile[32][33];
  int c0 = blockIdx.x * 32, r0 = blockIdx.y * 32;
  int tx = threadIdx.x, ty = threadIdx.y;
#pragma unroll
  for (int i = 0; i < 32; i += 8)
    tile[ty + i][tx] = inb[(size_t)(r0 + ty + i) * 1024 + c0 + tx];
  __syncthreads();
#pragma unroll
  for (int i = 0; i < 32; i += 8)
    outb[(size_t)(c0 + ty + i) * 2048 + r0 + tx] = tile[tx][ty + i];
}

// ---------------- masked row softmax over scores fp32, writes P bf16 in-place --
__global__ __launch_bounds__(256) void softmax_kernel(float* __restrict__ scores) {
  int row = blockIdx.x;
  int s = row & 2047;
  float* srow = scores + (size_t)row * 2048;
  int tid = threadIdx.x;
  int lane = tid & 63, wave = tid >> 6;
  const float FINF = __builtin_inff();
  float x[8];
  float m = -FINF;
#pragma unroll
  for (int i = 0; i < 8; i++) {
    int t = s + tid + i * 256;
    float v = -FINF;
    if (t < 2048) {
      v = srow[t];
      v = fminf(fmaxf(v, -1.0e9f), 1.0e9f);  // CLAMP
    }
    x[i] = v;
    m = fmaxf(m, v);
  }
#pragma unroll
  for (int o = 32; o >= 1; o >>= 1) m = fmaxf(m, __shfl_xor(m, o, 64));
  __shared__ float rm[4], rsum[4];
  if (lane == 0) rm[wave] = m;
  __syncthreads();
  m = fmaxf(fmaxf(rm[0], rm[1]), fmaxf(rm[2], rm[3]));
  float sum = 0.f;
#pragma unroll
  for (int i = 0; i < 8; i++) {
    x[i] = __expf(x[i] - m);
    sum += x[i];
  }
#pragma unroll
  for (int o = 32; o >= 1; o >>= 1) sum += __shfl_xor(sum, o, 64);
  if (lane == 0) rsum[wave] = sum;
  __syncthreads();
  sum = rsum[0] + rsum[1] + rsum[2] + rsum[3];
  float inv = 1.0f / sum;
  u16* prow = (u16*)srow;
  for (int t = tid; t < s; t += 256) prow[t] = 0;
#pragma unroll
  for (int i = 0; i < 8; i++) {
    int t = s + tid + i * 256;
    if (t < 2048) prow[t] = f2bf(x[i] * inv);
  }
}

// ---------------- 256x256 8-phase bf16 GEMM, B^T layout ----------------
// C[M,N] = A[M,K] * Bt[N,K]^T. BK=64, 8 waves (2Mx4N), wave tile 128x64.
// T2: st-swizzle (byte ^= (row&7)<<4) read-side + pre-swizzled global source.
// T3/T4: 8 phases per 2 K-tiles, counted vmcnt(4) at phases 4/8 only.
// T5: setprio around MFMA clusters.
// MODE 0: plain. MODE 1: QK (skip tj<ti; C routes bz>=4 -> Csplit).
// MODE 2: PV (k starts at ti*256; A routes bz>=4 -> Asplit).
template <int OUTF32, int MODE>
__global__ __launch_bounds__(512, 2) void gemm256(
    const u16* __restrict__ A, const u16* __restrict__ Asplit,
    const u16* __restrict__ B, void* __restrict__ Cv, void* __restrict__ Csplit,
    const float* __restrict__ bias, int K, int lda, int ldb, int ldc,
    float scale, long long sA, long long sB, long long sC) {
  const int ti = blockIdx.y, tj = blockIdx.x, bz = blockIdx.z;
  if (MODE == 1 && tj < ti) return;  // fully-masked score tile

  const u16* Ab = A + (size_t)bz * (size_t)sA;
  if (MODE == 2 && Asplit != nullptr && bz >= 4)
    Ab = Asplit + (size_t)(bz - 4) * (size_t)sA;
  const u16* Bb = B + (size_t)bz * (size_t)sB;
  void* Cp = Cv;
  size_t cbase = (size_t)bz * (size_t)sC;
  if (MODE == 1 && Csplit != nullptr && bz >= 4) {
    Cp = Csplit;
    cbase = (size_t)(bz - 4) * (size_t)sC;
  }

  __shared__ u16 As[2][256 * 64];  // 64 KiB
  __shared__ u16 Bs[2][256 * 64];  // 64 KiB

  const int tid = threadIdx.x;
  const int wave = tid >> 6, lane = tid & 63;
  const int wr = wave >> 2, wc = wave & 3;  // 2 x 4 wave grid
  const int fr = lane & 15;
  const int kb16 = (lane >> 4) * 16;        // byte offset of k-frag in 64B k-block
  const int swz = (fr & 7) << 4;
  const int cs0 = kb16 ^ swz;               // ks=0 swizzled col byte
  const int cs1 = (64 + kb16) ^ swz;        // ks=1
  const int aRowOff = (wr * 128 + fr) * 128;  // bytes
  const int bRowOff = (wc * 64 + fr) * 128;

  // staging per-thread precompute: 4 chunks of 16B per matrix per K-tile
  size_t gA[4], gB[4];
  u32 ldsOff[4];
#pragma unroll
  for (int l = 0; l < 4; ++l) {
    int c = l * 512 + tid;
    int row = c >> 3;
    int colb = (c & 7) << 4;
    int colg = colb ^ ((row & 7) << 4);  // pre-swizzled global source col
    gA[l] = (size_t)(ti * 256 + row) * lda + (colg >> 1);
    gB[l] = (size_t)(tj * 256 + row) * ldb + (colg >> 1);
    ldsOff[l] = (u32)c * 16;
  }

  const int k0 = (MODE == 2) ? ti * 256 : 0;
  const int niter = (K - k0) / 128;  // 2 K-tiles per iteration

  f32x4 acc[8][4] = {};
  bf16x8 aF[4][2], bF[4][2];

#define GLL(gaddr, laddr)                                        \
  __builtin_amdgcn_global_load_lds(                              \
      (const __attribute__((address_space(1))) void*)(gaddr),    \
      (__attribute__((address_space(3))) void*)(laddr), 16, 0, 0)

#define STAGE_A(buf, h, t)                                                  \
  do {                                                                      \
    const int _kt = k0 + (t) * 64;                                          \
    GLL(Ab + gA[(h)*2 + 0] + _kt, (char*)&As[buf][0] + ldsOff[(h)*2 + 0]);  \
    GLL(Ab + gA[(h)*2 + 1] + _kt, (char*)&As[buf][0] + ldsOff[(h)*2 + 1]);  \
  } while (0)
#define STAGE_B(buf, h, t)                                                  \
  do {                                                                      \
    const int _kt = k0 + (t) * 64;                                          \
    GLL(Bb + gB[(h)*2 + 0] + _kt, (char*)&Bs[buf][0] + ldsOff[(h)*2 + 0]);  \
    GLL(Bb + gB[(h)*2 + 1] + _kt, (char*)&Bs[buf][0] + ldsOff[(h)*2 + 1]);  \
  } while (0)

#define DS_A(buf, qm)                                                \
  do {                                                               \
    const char* _pa = (const char*)&As[buf][0] + aRowOff + (qm)*8192;\
    _Pragma("unroll") for (int mm = 0; mm < 4; ++mm) {               \
      aF[mm][0] = *(const bf16x8*)(_pa + mm * 2048 + cs0);           \
      aF[mm][1] = *(const bf16x8*)(_pa + mm * 2048 + cs1);           \
    }                                                                \
  } while (0)
#define DS_B(buf, nh)                                                \
  do {                                                               \
    const char* _pb = (const char*)&Bs[buf][0] + bRowOff;            \
    _Pragma("unroll") for (int nn = 0; nn < 2; ++nn) {               \
      bF[(nh)*2 + nn][0] = *(const bf16x8*)(_pb + ((nh)*2 + nn) * 2048 + cs0); \
      bF[(nh)*2 + nn][1] = *(const bf16x8*)(_pb + ((nh)*2 + nn) * 2048 + cs1); \
    }                                                                \
  } while (0)

#define MMA(qm, nh)                                                          \
  do {                                                                       \
    _Pragma("unroll") for (int mm = 0; mm < 4; ++mm)                         \
    _Pragma("unroll") for (int nn = 0; nn < 2; ++nn) {                       \
      f32x4 _c = acc[(qm)*4 + mm][(nh)*2 + nn];                              \
      _c = __builtin_amdgcn_mfma_f32_16x16x32_bf16(aF[mm][0], bF[(nh)*2+nn][0], _c, 0, 0, 0); \
      _c = __builtin_amdgcn_mfma_f32_16x16x32_bf16(aF[mm][1], bF[(nh)*2+nn][1], _c, 0, 0, 0); \
      acc[(qm)*4 + mm][(nh)*2 + nn] = _c;                                    \
    }                                                                        \
  } while (0)

#define BAR __builtin_amdgcn_s_barrier()
#define LGKM0 asm volatile("s_waitcnt lgkmcnt(0)" ::: "memory")
#define VM4 asm volatile("s_waitcnt vmcnt(4)" ::: "memory")
#define VM0 asm volatile("s_waitcnt vmcnt(0)" ::: "memory")
#define PRIO1 __builtin_amdgcn_s_setprio(1)
#define PRIO0 __builtin_amdgcn_s_setprio(0)

  // Prologue: tile0 (B then A, 8 loads) + tile1-B (4 loads); keep 4 in flight.
  STAGE_B(0, 0, 0); STAGE_B(0, 1, 0);
  STAGE_A(0, 0, 0); STAGE_A(0, 1, 0);
  STAGE_B(1, 0, 1); STAGE_B(1, 1, 1);
  VM4; BAR;

  for (int it = 0; it < niter; ++it) {
    const bool lastIt = (it == niter - 1);
    const int t1 = 2 * it + 1, t2 = 2 * it + 2, t3 = 2 * it + 3;

    // ---- P1: buf0 (qm0 x nh0); stage t1-A-h0 (buf1-A idle since prev P7)
    DS_A(0, 0); DS_B(0, 0);
    STAGE_A(1, 0, t1);
    BAR; LGKM0; PRIO1; MMA(0, 0); PRIO0; BAR;
    // ---- P2: buf0 (qm0 x nh1); stage t1-A-h1
    DS_B(0, 1);
    STAGE_A(1, 1, t1);
    BAR; LGKM0; PRIO1; MMA(0, 1); PRIO0; BAR;
    // ---- P3: buf0 (qm1 x nh0); buf0-B reads done after P2 -> stage t2-B-h0
    DS_A(0, 1);
    if (!lastIt) STAGE_B(0, 0, t2);
    BAR; LGKM0; PRIO1; MMA(1, 0); PRIO0; BAR;
    // ---- P4: buf0 (qm1 x nh1); stage t2-B-h1; K-tile wait
    if (!lastIt) STAGE_B(0, 1, t2);
    BAR; PRIO1; MMA(1, 1); PRIO0;
    if (lastIt) { VM0; } else { VM4; }  // guarantees t1 (buf1) fully landed
    BAR;
    // ---- P5: buf1 (qm0 x nh0); buf0-A reads done after P3 -> stage t2-A-h0
    DS_A(1, 0); DS_B(1, 0);
    if (!lastIt) STAGE_A(0, 0, t2);
    BAR; LGKM0; PRIO1; MMA(0, 0); PRIO0; BAR;
    // ---- P6: buf1 (qm0 x nh1); stage t2-A-h1
    DS_B(1, 1);
    if (!lastIt) STAGE_A(0, 1, t2);
    BAR; LGKM0; PRIO1; MMA(0, 1); PRIO0; BAR;
    // ---- P7: buf1 (qm1 x nh0); buf1-B reads done after P6 -> stage t3-B-h0
    DS_A(1, 1);
    if (!lastIt) STAGE_B(1, 0, t3);
    BAR; LGKM0; PRIO1; MMA(1, 0); PRIO0; BAR;
    // ---- P8: buf1 (qm1 x nh1); stage t3-B-h1; K-tile wait
    if (!lastIt) STAGE_B(1, 1, t3);
    BAR; PRIO1; MMA(1, 1); PRIO0;
    if (!lastIt) VM4;  // guarantees t2 (buf0) fully landed
    BAR;
  }

  // Epilogue: C/D layout col=lane&15, row=(lane>>4)*4+j
  const int orow0 = ti * 256 + wr * 128 + ((lane >> 4) << 2);
  const int ocol0 = tj * 256 + wc * 64 + fr;
#pragma unroll
  for (int m = 0; m < 8; ++m) {
#pragma unroll
    for (int n = 0; n < 4; ++n) {
      const int col = ocol0 + n * 16;
      const float bv = bias ? bias[col] : 0.0f;
#pragma unroll
      for (int j = 0; j < 4; ++j) {
        const int row = orow0 + m * 16 + j;
        const float v = acc[m][n][j] * scale + bv;
        const size_t idx = cbase + (size_t)row * ldc + col;
        if (OUTF32) ((float*)Cp)[idx] = v;
        else        ((u16*)Cp)[idx]   = f2bf(v);
      }
    }
  }
#undef GLL
#undef STAGE_A
#undef STAGE_B
#undef DS_A
#undef DS_B
#undef MMA
#undef BAR
#undef LGKM0
#undef VM4
#undef VM0
#undef PRIO1
#undef PRIO0
}

extern "C" void kernel_launch(void* const* d_in, const int* in_sizes, int n_in,
                              void* d_out, int out_size, void* d_ws, size_t ws_size,
                              hipStream_t stream) {
  (void)in_sizes; (void)n_in; (void)out_size;
  const float* x   = (const float*)d_in[0];
  const float* lnw = (const float*)d_in[1];
  const float* lnb = (const float*)d_in[2];
  const float* wq  = (const float*)d_in[3];
  const float* bq  = (const float*)d_in[4];
  const float* wk  = (const float*)d_in[5];
  const float* bk  = (const float*)d_in[6];
  const float* wv  = (const float*)d_in[7];
  const float* bv  = (const float*)d_in[8];
  const float* w0  = (const float*)d_in[9];
  const float* b0  = (const float*)d_in[10];
  float* out = (float*)d_out;

  const size_t ROWS = 16384;  // B*S
  char* ws = (char*)d_ws;
  size_t off = 0;
  auto alloc = [&](size_t bytes) -> void* {
    void* p = ws + off;
    off += (bytes + 255) & ~(size_t)255;
    return p;
  };
  u16* xn  = (u16*)alloc(ROWS * 1024 * 2);
  u16* wqt = (u16*)alloc((size_t)1024 * 1024 * 2);
  u16* wkt = (u16*)alloc((size_t)1024 * 1024 * 2);
  u16* wvt = (u16*)alloc((size_t)1024 * 1024 * 2);
  u16* w0t = (u16*)alloc((size_t)1024 * 1024 * 2);
  u16* Q   = (u16*)alloc(ROWS * 1024 * 2);
  u16* Km  = (u16*)alloc(ROWS * 1024 * 2);
  u16* V   = (u16*)alloc(ROWS * 1024 * 2);
  u16* Vt  = (u16*)alloc(ROWS * 1024 * 2);
  u16* H   = (u16*)alloc(ROWS * 1024 * 2);

  // scores: batches 0-3 always in d_out (exactly 64MB); batches 4-7 in ws if room
  const size_t SC4 = (size_t)4 * 2048 * 2048 * 4;  // 64 MB
  float* sc0 = (float*)d_out;
  bool onePass = (ws_size >= off + SC4);
  float* sc1 = onePass ? (float*)(ws + off) : nullptr;

  ln_kernel<<<dim3(16384), dim3(256), 0, stream>>>(x, lnw, lnb, xn);
  dim3 tb(32, 8);
  transpose_w<<<dim3(32, 32), tb, 0, stream>>>(wq, wqt, 1024, 1024);
  transpose_w<<<dim3(32, 32), tb, 0, stream>>>(wk, wkt, 1024, 1024);
  transpose_w<<<dim3(32, 32), tb, 0, stream>>>(wv, wvt, 1024, 1024);
  transpose_w<<<dim3(32, 32), tb, 0, stream>>>(w0, w0t, 1024, 1024);

  // Projections: M=16384, N=1024, K=1024
  gemm256<0, 0><<<dim3(4, 64, 1), dim3(512), 0, stream>>>(
      xn, nullptr, wqt, Q, nullptr, bq, 1024, 1024, 1024, 1024, 1.0f, 0, 0, 0);
  gemm256<0, 0><<<dim3(4, 64, 1), dim3(512), 0, stream>>>(
      xn, nullptr, wkt, Km, nullptr, bk, 1024, 1024, 1024, 1024, 1.0f, 0, 0, 0);
  gemm256<0, 0><<<dim3(4, 64, 1), dim3(512), 0, stream>>>(
      xn, nullptr, wvt, V, nullptr, bv, 1024, 1024, 1024, 1024, 1.0f, 0, 0, 0);

  transpose_v<<<dim3(32, 64, 8), tb, 0, stream>>>(V, Vt);

  float qk_scale = (float)(1.0 / (std::sqrt(1024.0) + 1e-9));
  const long long sQ = 2048LL * 1024, sS = 2048LL * 2048, sP = 2048LL * 4096,
                  sVt = 1024LL * 2048;

  if (onePass) {
    gemm256<1, 1><<<dim3(8, 8, 8), dim3(512), 0, stream>>>(
        Q, nullptr, Km, sc0, sc1, nullptr, 1024, 1024, 1024, 2048, qk_scale,
        sQ, sQ, sS);
    softmax_kernel<<<dim3(8192), dim3(256), 0, stream>>>(sc0);
    softmax_kernel<<<dim3(8192), dim3(256), 0, stream>>>(sc1);
    gemm256<0, 2><<<dim3(4, 8, 8), dim3(512), 0, stream>>>(
        (const u16*)sc0, (const u16*)sc1, Vt, H, nullptr, nullptr,
        2048, 4096, 2048, 1024, 1.0f, sP, sVt, sQ);
  } else {
    for (int p = 0; p < 2; ++p) {
      const size_t bo = (size_t)p * 4;
      gemm256<1, 1><<<dim3(8, 8, 4), dim3(512), 0, stream>>>(
          Q + bo * sQ, nullptr, Km + bo * sQ, sc0, nullptr, nullptr,
          1024, 1024, 1024, 2048, qk_scale, sQ, sQ, sS);
      softmax_kernel<<<dim3(8192), dim3(256), 0, stream>>>(sc0);
      gemm256<0, 2><<<dim3(4, 8, 4), dim3(512), 0, stream>>>(
          (const u16*)sc0, nullptr, Vt + bo * sVt, H + bo * sQ, nullptr, nullptr,
          2048, 4096, 2048, 1024, 1.0f, sP, sVt, sQ);
    }
  }

  // Output projection: writes all of d_out (overwrites scores scratch)
  gemm256<1, 0><<<dim3(4, 64, 1), dim3(512), 0, stream>>>(
      H, nullptr, w0t, (void*)out, nullptr, b0, 1024, 1024, 1024, 1024, 1.0f,
      0, 0, 0);
}